// Round 1
// baseline (691.799 us; speedup 1.0000x reference)
//
#include <hip/hip_runtime.h>
#include <cmath>

// Tree: complete binary tree, level order. Levels 0..20.
// Level d occupies [2^d - 1, 2^{d+1} - 1). Leaves = level 20 (2^20 nodes).
#define N_NODES_C   ((1 << 21) - 1)   // 2097151
#define N_LEAVES_C  (1 << 20)         // 1048576
#define LEAF_START  (N_LEAVES_C - 1)  // 1048575
#define NFEAT       64

__device__ __forceinline__ float score_fn(float dot, float bias) {
    return 1.0f + tanhf(dot + bias) * 0.1f;  // 1/TANH_SCALAR
}

// scores[node] = 1 + tanh(features[node,:] . W + b)/10
// 16 lanes per node, one float4 per lane -> 16B/lane fully coalesced.
__global__ __launch_bounds__(256) void scores_kernel(
        const float* __restrict__ features,
        const float* __restrict__ W,
        const float* __restrict__ b,
        float* __restrict__ scores) {
    const int q = threadIdx.x & 15;                     // lane within 16-group
    const float4 w4 = ((const float4*)W)[q];            // W[4q..4q+3], broadcast-cached
    const float bias = b[0];
    const int group0 = (blockIdx.x * 256 + threadIdx.x) >> 4;  // node id
    const int stride = (gridDim.x * 256) >> 4;
    for (int node = group0; node < N_NODES_C; node += stride) {
        const float4 f = ((const float4*)(features + (size_t)node * NFEAT))[q];
        float v = f.x * w4.x + f.y * w4.y + f.z * w4.z + f.w * w4.w;
        // butterfly over the 16-lane group (xor masks stay inside the group)
        v += __shfl_xor(v, 1);
        v += __shfl_xor(v, 2);
        v += __shfl_xor(v, 4);
        v += __shfl_xor(v, 8);
        if (q == 0) scores[node] = score_fn(v, bias);
    }
}

// One block = 4096 leaves; reduce levels 19..8 locally in LDS (ping-pong).
// Writes out[] for leaves and for every node at levels 19..8 of its subtree.
__global__ __launch_bounds__(256) void stage1_kernel(
        const float* __restrict__ scores,
        const float* __restrict__ leaf_energy,
        float* __restrict__ out) {
    __shared__ float buf[2][4096];
    const int blk = blockIdx.x;          // 256 blocks
    const int tid = threadIdx.x;
    const int leaf_off = blk * 4096;

    // Leaf level: copy energies out, contributions into LDS.
    for (int i = tid; i < 4096; i += 256) {
        const int g = LEAF_START + leaf_off + i;
        const float e = leaf_energy[leaf_off + i];
        out[g] = e;
        buf[0][i] = scores[g] * e;
    }
    __syncthreads();

    int p = 0;
    // pd = parent level; m = parents this block produces at level pd.
    for (int pd = 19; pd >= 8; --pd) {
        const int m = 1 << (pd - 8);                  // 2048 .. 1
        const int base = (1 << pd) - 1 + blk * m;     // global index of first parent
        for (int j = tid; j < m; j += 256) {
            const float val = buf[p][2 * j] + buf[p][2 * j + 1];
            out[base + j] = val;
            buf[1 - p][j] = scores[base + j] * val;   // contribution for next level
        }
        p ^= 1;
        __syncthreads();
    }
}

// One block finishes levels 7..0 from the 256 level-8 energies in out[255..511).
__global__ __launch_bounds__(256) void stage2_kernel(
        const float* __restrict__ scores,
        float* __restrict__ out) {
    __shared__ float buf[2][256];
    const int tid = threadIdx.x;
    buf[0][tid] = scores[255 + tid] * out[255 + tid];
    __syncthreads();
    int p = 0;
    for (int pd = 7; pd >= 0; --pd) {
        const int m = 1 << pd;
        const int base = m - 1;
        if (tid < m) {
            const float val = buf[p][2 * tid] + buf[p][2 * tid + 1];
            out[base + tid] = val;
            buf[1 - p][tid] = scores[base + tid] * val;
        }
        p ^= 1;
        __syncthreads();
    }
}

extern "C" void kernel_launch(void* const* d_in, const int* in_sizes, int n_in,
                              void* d_out, int out_size, void* d_ws, size_t ws_size,
                              hipStream_t stream) {
    const float* features    = (const float*)d_in[0];  // [N_NODES, 64]
    const float* leaf_energy = (const float*)d_in[1];  // [N_LEAVES]
    const float* W           = (const float*)d_in[2];  // [64]
    const float* b           = (const float*)d_in[3];  // [1]
    float* out    = (float*)d_out;                     // [N_NODES]
    float* scores = (float*)d_ws;                      // N_NODES floats (8.4 MB scratch)

    // 32768 blocks -> ~4 grid-stride iterations per 16-lane group.
    scores_kernel<<<32768, 256, 0, stream>>>(features, W, b, scores);
    stage1_kernel<<<256, 256, 0, stream>>>(scores, leaf_energy, out);
    stage2_kernel<<<1, 256, 0, stream>>>(scores, out);
}